// Round 2
// baseline (1022.169 us; speedup 1.0000x reference)
//
#include <hip/hip_runtime.h>
#include <math.h>

// Fused attention block: QKV proj -> per-head RMSNorm -> RoPE (+q_gain) ->
// GQA causal flash attention -> output proj.
// I/O is FP32 (threshold = 2% of max|ref| -> bf16 internal compute is fine).
// Pipeline: convert fp32->bf16, bf16 MFMA GEMMs (fp32 accum), final proj
// GEMM writes fp32 to d_out.
//
// Shapes: B=4 T=2048 H=16 KVH=4 HD=128 D=2048 KVD=512.

typedef float f32x4 __attribute__((ext_vector_type(4)));
typedef __bf16 bf16x8 __attribute__((ext_vector_type(8)));
typedef __bf16 bf16x4 __attribute__((ext_vector_type(4)));

__device__ __forceinline__ void load_lds16(const __bf16* g, __bf16* l) {
    __builtin_amdgcn_global_load_lds(
        (const __attribute__((address_space(1))) void*)g,
        (__attribute__((address_space(3))) void*)l, 16, 0, 0);
}

// ---------------------------------------------------------------------------
// fp32 -> bf16 conversion (n divisible by 4)
// ---------------------------------------------------------------------------
__global__ __launch_bounds__(256) void cvt_f32_bf16(
    const float* __restrict__ src, __bf16* __restrict__ dst, int n)
{
    int i = (blockIdx.x * 256 + threadIdx.x) * 4;
    if (i < n) {
        float4 v = *(const float4*)(src + i);
        bf16x4 o = {(__bf16)v.x, (__bf16)v.y, (__bf16)v.z, (__bf16)v.w};
        *(bf16x4*)(dst + i) = o;
    }
}

// ---------------------------------------------------------------------------
// GEMM: C[M][N] = A[M][K] * W[N][K]^T   (row-major, bf16 in, OutT out)
// 128x128 tile, BK=32, 256 threads (4 waves, each 64x64 quadrant).
// ---------------------------------------------------------------------------
template <typename OutT>
__global__ __launch_bounds__(256) void gemm_bt(
    const __bf16* __restrict__ A, const __bf16* __restrict__ W,
    OutT* __restrict__ C, int M, int N, int K)
{
    const int bn = blockIdx.x, bm = blockIdx.y;
    const int tid = threadIdx.x;
    const int wave = tid >> 6, lane = tid & 63;
    const int quad = lane >> 4, l16 = lane & 15;

    __shared__ __bf16 As[128 * 32];
    __shared__ __bf16 Ws[128 * 32];

    const int wm = (wave & 1) * 64;   // wave's row quadrant
    const int wn = (wave >> 1) * 64;  // wave's col quadrant

    f32x4 acc[4][4] = {};

    const int srow = wave * 16 + (lane >> 2);   // + r*64
    const int scol = (lane & 3) * 8;

    const __bf16* Ag = A + (size_t)(bm * 128) * K + scol;
    const __bf16* Wg = W + (size_t)(bn * 128) * K + scol;

    for (int k0 = 0; k0 < K; k0 += 32) {
        __syncthreads();
#pragma unroll
        for (int r = 0; r < 2; ++r) {
            load_lds16(Ag + (size_t)(srow + r * 64) * K + k0, As + (r * 4 + wave) * 512);
            load_lds16(Wg + (size_t)(srow + r * 64) * K + k0, Ws + (r * 4 + wave) * 512);
        }
        __syncthreads();

        bf16x8 af[4], wf[4];
#pragma unroll
        for (int i = 0; i < 4; ++i) {
            af[i] = *(const bf16x8*)(As + (wm + i * 16 + l16) * 32 + quad * 8);
            wf[i] = *(const bf16x8*)(Ws + (wn + i * 16 + l16) * 32 + quad * 8);
        }
#pragma unroll
        for (int mi = 0; mi < 4; ++mi)
#pragma unroll
            for (int ni = 0; ni < 4; ++ni)
                acc[mi][ni] = __builtin_amdgcn_mfma_f32_16x16x32_bf16(
                    af[mi], wf[ni], acc[mi][ni], 0, 0, 0);
    }

    // epilogue: C/D layout col=l16, row=quad*4+r  (m89/m91-verified)
#pragma unroll
    for (int mi = 0; mi < 4; ++mi) {
#pragma unroll
        for (int r = 0; r < 4; ++r) {
            int row = bm * 128 + wm + mi * 16 + quad * 4 + r;
            OutT* Cp = C + (size_t)row * N + bn * 128 + wn + l16;
#pragma unroll
            for (int ni = 0; ni < 4; ++ni)
                Cp[ni * 16] = (OutT)acc[mi][ni][r];
        }
    }
}

// ---------------------------------------------------------------------------
// Per-head RMSNorm + RoPE (+ q_gain).  One wave per 128-elem head row.
// Rows [0, B*T*H) are q rows; rows [B*T*H, B*T*H + B*T*KVH) are k rows.
// ---------------------------------------------------------------------------
__global__ __launch_bounds__(256) void qk_norm_rope(
    __bf16* __restrict__ q, __bf16* __restrict__ k,
    const float* __restrict__ q_gain)
{
    const int row = blockIdx.x * 4 + (threadIdx.x >> 6);
    const int lane = threadIdx.x & 63;
    const int BTH = 4 * 2048 * 16;

    __bf16* base;
    int t;
    float gain;
    if (row < BTH) {
        int bt = row >> 4, h = row & 15;
        base = q + (size_t)bt * 2048 + h * 128;
        t = bt & 2047;
        gain = q_gain[h];
    } else {
        int r2 = row - BTH;
        int bt = r2 >> 2, kvh = r2 & 3;
        base = k + (size_t)bt * 512 + kvh * 128;
        t = bt & 2047;
        gain = 1.0f;
    }

    float x0 = (float)base[lane];        // d = lane
    float x1 = (float)base[lane + 64];   // d = lane + 64

    float ss = x0 * x0 + x1 * x1;
#pragma unroll
    for (int off = 32; off; off >>= 1) ss += __shfl_xor(ss, off);
    float inv = rsqrtf(ss * (1.0f / 128.0f) + 1.1920928955078125e-07f);
    x0 *= inv; x1 *= inv;

    // inv_freq = 10000^(-lane/64) = 2^(-lane * log2(10000)/64)
    float freq = exp2f(-(float)lane * 0.20762050593046013f);
    float ang = (float)t * freq;
    float s, c;
    sincosf(ang, &s, &c);
    float o0 = x0 * c - x1 * s;
    float o1 = x1 * c + x0 * s;
    base[lane]      = (__bf16)(o0 * gain);
    base[lane + 64] = (__bf16)(o1 * gain);
}

// ---------------------------------------------------------------------------
// V transpose: vt[b][c][t] = v[b][t][c]   (c = kvh*128+d in [0,512))
// ---------------------------------------------------------------------------
__global__ __launch_bounds__(256) void transpose_v(
    const __bf16* __restrict__ v, __bf16* __restrict__ vtout)
{
    __shared__ __bf16 tile[64][65];
    const int b = blockIdx.z;
    const int t0 = blockIdx.x * 64, c0 = blockIdx.y * 64;
    const __bf16* vb = v + (size_t)b * 2048 * 512;
    __bf16* vtb = vtout + (size_t)b * 512 * 2048;
    const int j = threadIdx.x & 63;
    const int r0 = threadIdx.x >> 6;
#pragma unroll
    for (int i = 0; i < 16; ++i) {
        int r = r0 + i * 4;
        tile[r][j] = vb[(size_t)(t0 + r) * 512 + c0 + j];
    }
    __syncthreads();
#pragma unroll
    for (int i = 0; i < 16; ++i) {
        int r = r0 + i * 4;
        vtb[(size_t)(c0 + r) * 2048 + t0 + j] = tile[j][r];
    }
}

// ---------------------------------------------------------------------------
// Flash attention (causal, GQA).  Block = (qtile, b*H+h), 256 threads.
// Q tile 64x128 resident; loop KV tiles of 64: S=QK^T -> online softmax ->
// P through per-wave LDS (C-layout -> A-layout) -> PV accumulate.
// ---------------------------------------------------------------------------
__global__ __launch_bounds__(256) void attn(
    const __bf16* __restrict__ q, const __bf16* __restrict__ k,
    const __bf16* __restrict__ vt, __bf16* __restrict__ y)
{
    const int qt = blockIdx.x;       // 0..31
    const int bh = blockIdx.y;       // 0..63
    const int b = bh >> 4, h = bh & 15, kvh = h >> 2;
    const int tid = threadIdx.x;
    const int wave = tid >> 6, lane = tid & 63;
    const int quad = lane >> 4, l16 = lane & 15;

    __shared__ __bf16 Qs[64 * 128];
    __shared__ __bf16 Ks[64 * 128];
    __shared__ __bf16 Vts[128 * 64];
    __shared__ __bf16 Ps[4 * 16 * 64];

    const int qt0 = qt * 64;
    const size_t qbase = ((size_t)b * 2048 + qt0) * 2048 + h * 128;

    // stage Q tile [64][128]
    {
        const int rq = lane >> 4, cq = (lane & 15) * 8;
#pragma unroll
        for (int r = 0; r < 4; ++r) {
            int rr = (r * 4 + wave) * 4 + rq;
            load_lds16(q + qbase + (size_t)rr * 2048 + cq, Qs + (r * 4 + wave) * 512);
        }
    }
    __syncthreads();

    const int wq = wave * 16;  // this wave's 16 q-rows (local)
    bf16x8 qf[4];
#pragma unroll
    for (int t = 0; t < 4; ++t)
        qf[t] = *(const bf16x8*)(Qs + (wq + l16) * 128 + t * 32 + quad * 8);

    f32x4 oacc[8] = {};
    float mrow[4], lrow[4];
#pragma unroll
    for (int r = 0; r < 4; ++r) { mrow[r] = -3.0e38f; lrow[r] = 0.f; }

    const float sm_scale = 0.08838834764831845f * 1.4426950408889634f; // 1/sqrt(128)*log2(e)

    const size_t kbase = (size_t)b * 2048 * 512 + kvh * 128;
    const size_t vtbase = (size_t)(b * 4 + kvh) * 128 * 2048;

    for (int jt = 0; jt <= qt; ++jt) {
        const int j0 = jt * 64;
        __syncthreads();
        {
            const int rk = lane >> 4, ck = (lane & 15) * 8;
            const int rv = lane >> 3, cv = (lane & 7) * 8;
#pragma unroll
            for (int r = 0; r < 4; ++r) {
                load_lds16(k + kbase + (size_t)(j0 + (r * 4 + wave) * 4 + rk) * 512 + ck,
                           Ks + (r * 4 + wave) * 512);
                load_lds16(vt + vtbase + (size_t)((r * 4 + wave) * 8 + rv) * 2048 + j0 + cv,
                           Vts + (r * 4 + wave) * 512);
            }
        }
        __syncthreads();

        // S strip (16 q-rows x 64 kv-cols) for this wave
        f32x4 sacc[4] = {};
#pragma unroll
        for (int nt = 0; nt < 4; ++nt) {
#pragma unroll
            for (int t = 0; t < 4; ++t) {
                bf16x8 kf = *(const bf16x8*)(Ks + (nt * 16 + l16) * 128 + t * 32 + quad * 8);
                sacc[nt] = __builtin_amdgcn_mfma_f32_16x16x32_bf16(qf[t], kf, sacc[nt], 0, 0, 0);
            }
        }

        if (jt == qt) {  // diagonal tile: causal mask
#pragma unroll
            for (int nt = 0; nt < 4; ++nt) {
                int kg = nt * 16 + l16;
#pragma unroll
                for (int r = 0; r < 4; ++r) {
                    int qg = wq + quad * 4 + r;
                    if (kg > qg) sacc[nt][r] = -3.0e38f;
                }
            }
        }

        // online softmax (row data lives across the 16 lanes sharing `quad`)
        float alpha[4];
        float p[4][4];
#pragma unroll
        for (int r = 0; r < 4; ++r) {
            float mx = fmaxf(fmaxf(sacc[0][r], sacc[1][r]), fmaxf(sacc[2][r], sacc[3][r]));
#pragma unroll
            for (int off = 8; off; off >>= 1) mx = fmaxf(mx, __shfl_xor(mx, off));
            float mnew = fmaxf(mrow[r], mx);
            alpha[r] = exp2f((mrow[r] - mnew) * sm_scale);
            mrow[r] = mnew;
            float sum = 0.f;
#pragma unroll
            for (int nt = 0; nt < 4; ++nt) {
                float pv = exp2f((sacc[nt][r] - mnew) * sm_scale);
                p[nt][r] = pv;
                sum += pv;
            }
#pragma unroll
            for (int off = 8; off; off >>= 1) sum += __shfl_xor(sum, off);
            lrow[r] = lrow[r] * alpha[r] + sum;
        }

        // P: C-layout -> LDS -> A-layout (per-wave buffer; same-wave DS ops
        // are ordered, no barrier needed)
        __bf16* Pw = Ps + wave * 1024;
#pragma unroll
        for (int nt = 0; nt < 4; ++nt)
#pragma unroll
            for (int r = 0; r < 4; ++r)
                Pw[(quad * 4 + r) * 64 + nt * 16 + l16] = (__bf16)p[nt][r];

#pragma unroll
        for (int vn = 0; vn < 8; ++vn)
#pragma unroll
            for (int r = 0; r < 4; ++r)
                oacc[vn][r] *= alpha[r];

#pragma unroll
        for (int kt = 0; kt < 2; ++kt) {
            bf16x8 pf = *(const bf16x8*)(Pw + l16 * 64 + kt * 32 + quad * 8);
#pragma unroll
            for (int vn = 0; vn < 8; ++vn) {
                bf16x8 vf = *(const bf16x8*)(Vts + (vn * 16 + l16) * 64 + kt * 32 + quad * 8);
                oacc[vn] = __builtin_amdgcn_mfma_f32_16x16x32_bf16(pf, vf, oacc[vn], 0, 0, 0);
            }
        }
    }

    // epilogue: y[b][t][h*128+d]
    const size_t ybase = ((size_t)b * 2048 + qt0 + wq) * 2048 + h * 128;
#pragma unroll
    for (int r = 0; r < 4; ++r) {
        float inv = 1.0f / lrow[r];
        __bf16* yp = y + ybase + (size_t)(quad * 4 + r) * 2048 + l16;
#pragma unroll
        for (int vn = 0; vn < 8; ++vn)
            yp[vn * 16] = (__bf16)(oacc[vn][r] * inv);
    }
}

// ---------------------------------------------------------------------------
extern "C" void kernel_launch(void* const* d_in, const int* in_sizes, int n_in,
                              void* d_out, int out_size, void* d_ws, size_t ws_size,
                              hipStream_t stream) {
    const float* x     = (const float*)d_in[0];
    const float* Wq    = (const float*)d_in[1];
    const float* Wk    = (const float*)d_in[2];
    const float* Wv    = (const float*)d_in[3];
    const float* Wproj = (const float*)d_in[4];
    const float* qgain = (const float*)d_in[5];
    float* outp = (float*)d_out;

    // workspace layout (bf16 elems); ~113 MB total
    __bf16* xb  = (__bf16*)d_ws;          // 16777216
    __bf16* Wqb = xb  + 16777216;         // 4194304
    __bf16* Wkb = Wqb + 4194304;          // 1048576
    __bf16* Wvb = Wkb + 1048576;          // 1048576
    __bf16* Wpb = Wvb + 1048576;          // 4194304
    __bf16* q   = Wpb + 4194304;          // 16777216
    __bf16* k   = q   + 16777216;         // 4194304
    __bf16* v   = k   + 4194304;          // 4194304
    __bf16* vt  = v   + 4194304;          // 4194304
    __bf16* y   = q;                      // alias: 1:1 tile correspondence, safe

    dim3 blk(256);
    cvt_f32_bf16<<<dim3(16777216 / 1024), blk, 0, stream>>>(x, xb, 16777216);
    cvt_f32_bf16<<<dim3(4194304 / 1024), blk, 0, stream>>>(Wq, Wqb, 4194304);
    cvt_f32_bf16<<<dim3(1048576 / 1024), blk, 0, stream>>>(Wk, Wkb, 1048576);
    cvt_f32_bf16<<<dim3(1048576 / 1024), blk, 0, stream>>>(Wv, Wvb, 1048576);
    cvt_f32_bf16<<<dim3(4194304 / 1024), blk, 0, stream>>>(Wproj, Wpb, 4194304);

    gemm_bt<__bf16><<<dim3(16, 64), blk, 0, stream>>>(xb, Wqb, q, 8192, 2048, 2048);
    gemm_bt<__bf16><<<dim3(4, 64), blk, 0, stream>>>(xb, Wkb, k, 8192, 512, 2048);
    gemm_bt<__bf16><<<dim3(4, 64), blk, 0, stream>>>(xb, Wvb, v, 8192, 512, 2048);
    qk_norm_rope<<<dim3((4 * 2048 * (16 + 4)) / 4), blk, 0, stream>>>(q, k, qgain);
    transpose_v<<<dim3(32, 8, 4), blk, 0, stream>>>(v, vt);
    attn<<<dim3(32, 64), blk, 0, stream>>>(q, k, vt, y);
    gemm_bt<float><<<dim3(16, 64), blk, 0, stream>>>(y, Wpb, outp, 8192, 2048, 2048);
}

// Round 3
// 650.558 us; speedup vs baseline: 1.5712x; 1.5712x over previous
//
#include <hip/hip_runtime.h>
#include <math.h>

// Fused attention block: QKV proj -> per-head RMSNorm -> RoPE (+q_gain) ->
// GQA causal flash attention -> output proj.  FP32 I/O, bf16 MFMA internal.
//
// Shapes: B=4 T=2048 H=16 KVH=4 HD=128 D=2048 KVD=512.
//
// R3 changes vs R2 (attn was 575us of 1022us, MfmaUtil 5%, 9.5e7 LDS bank
// conflicts, occupancy 11.7%):
//  - XOR-swizzled LDS layouts for K/V^T/P (row-stride was 0 mod 32 banks ->
//    16-way degenerate reads; swizzle makes every ds_read_b128 8-phase min).
//  - Q fragments loaded global->VGPR directly (A-layout is 16B/lane
//    contiguous); Qs LDS dropped: 56KB -> 40KB -> 4 blocks/CU.
//  - Fixed-max softmax: RMSNorm bounds |s| <= 11.4*|gain| -> m=11.5*|gain|
//    constant; removes max/sum shuffle chains + oacc rescale per iter;
//    l-sum reduced once at end.
//  - K and V projections fused into one GEMM writing kv[8192][1024].
//  - attn blocks launched biggest-qt-first (tail balance).

typedef float f32x4 __attribute__((ext_vector_type(4)));
typedef __bf16 bf16x8 __attribute__((ext_vector_type(8)));
typedef __bf16 bf16x4 __attribute__((ext_vector_type(4)));

__device__ __forceinline__ void load_lds16(const __bf16* g, __bf16* l) {
    __builtin_amdgcn_global_load_lds(
        (const __attribute__((address_space(1))) void*)g,
        (__attribute__((address_space(3))) void*)l, 16, 0, 0);
}

// ---------------------------------------------------------------------------
// fp32 -> bf16 conversion (n divisible by 4)
// ---------------------------------------------------------------------------
__global__ __launch_bounds__(256) void cvt_f32_bf16(
    const float* __restrict__ src, __bf16* __restrict__ dst, int n)
{
    int i = (blockIdx.x * 256 + threadIdx.x) * 4;
    if (i < n) {
        float4 v = *(const float4*)(src + i);
        bf16x4 o = {(__bf16)v.x, (__bf16)v.y, (__bf16)v.z, (__bf16)v.w};
        *(bf16x4*)(dst + i) = o;
    }
}

// ---------------------------------------------------------------------------
// GEMM: C[M][N] = A[M][K] * W[N][K]^T   (row-major, bf16 in, OutT out)
// 128x128 tile, BK=32, 256 threads (4 waves, each 64x64 quadrant).
// ---------------------------------------------------------------------------
template <typename OutT>
__global__ __launch_bounds__(256) void gemm_bt(
    const __bf16* __restrict__ A, const __bf16* __restrict__ W,
    OutT* __restrict__ C, int M, int N, int K)
{
    const int bn = blockIdx.x, bm = blockIdx.y;
    const int tid = threadIdx.x;
    const int wave = tid >> 6, lane = tid & 63;
    const int quad = lane >> 4, l16 = lane & 15;

    __shared__ __bf16 As[128 * 32];
    __shared__ __bf16 Ws[128 * 32];

    const int wm = (wave & 1) * 64;
    const int wn = (wave >> 1) * 64;

    f32x4 acc[4][4] = {};

    const int srow = wave * 16 + (lane >> 2);   // + r*64
    const int scol = (lane & 3) * 8;

    const __bf16* Ag = A + (size_t)(bm * 128) * K + scol;
    const __bf16* Wg = W + (size_t)(bn * 128) * K + scol;

    for (int k0 = 0; k0 < K; k0 += 32) {
        __syncthreads();
#pragma unroll
        for (int r = 0; r < 2; ++r) {
            load_lds16(Ag + (size_t)(srow + r * 64) * K + k0, As + (r * 4 + wave) * 512);
            load_lds16(Wg + (size_t)(srow + r * 64) * K + k0, Ws + (r * 4 + wave) * 512);
        }
        __syncthreads();

        bf16x8 af[4], wf[4];
#pragma unroll
        for (int i = 0; i < 4; ++i) {
            af[i] = *(const bf16x8*)(As + (wm + i * 16 + l16) * 32 + quad * 8);
            wf[i] = *(const bf16x8*)(Ws + (wn + i * 16 + l16) * 32 + quad * 8);
        }
#pragma unroll
        for (int mi = 0; mi < 4; ++mi)
#pragma unroll
            for (int ni = 0; ni < 4; ++ni)
                acc[mi][ni] = __builtin_amdgcn_mfma_f32_16x16x32_bf16(
                    af[mi], wf[ni], acc[mi][ni], 0, 0, 0);
    }

    // epilogue: C/D layout col=l16, row=quad*4+r
#pragma unroll
    for (int mi = 0; mi < 4; ++mi) {
#pragma unroll
        for (int r = 0; r < 4; ++r) {
            int row = bm * 128 + wm + mi * 16 + quad * 4 + r;
            OutT* Cp = C + (size_t)row * N + bn * 128 + wn + l16;
#pragma unroll
            for (int ni = 0; ni < 4; ++ni)
                Cp[ni * 16] = (OutT)acc[mi][ni][r];
        }
    }
}

// ---------------------------------------------------------------------------
// Per-head RMSNorm + RoPE (+ q_gain).  One wave per 128-elem head row.
// q: [B*T][2048] (16 heads).  kv: [B*T][1024], cols 0..511 = k heads.
// ---------------------------------------------------------------------------
__global__ __launch_bounds__(256) void qk_norm_rope(
    __bf16* __restrict__ q, __bf16* __restrict__ kv,
    const float* __restrict__ q_gain)
{
    const int row = blockIdx.x * 4 + (threadIdx.x >> 6);
    const int lane = threadIdx.x & 63;
    const int BTH = 4 * 2048 * 16;

    __bf16* base;
    int t;
    float gain;
    if (row < BTH) {
        int bt = row >> 4, h = row & 15;
        base = q + (size_t)bt * 2048 + h * 128;
        t = bt & 2047;
        gain = q_gain[h];
    } else {
        int r2 = row - BTH;
        int bt = r2 >> 2, kvh = r2 & 3;
        base = kv + (size_t)bt * 1024 + kvh * 128;
        t = bt & 2047;
        gain = 1.0f;
    }

    float x0 = (float)base[lane];        // d = lane
    float x1 = (float)base[lane + 64];   // d = lane + 64

    float ss = x0 * x0 + x1 * x1;
#pragma unroll
    for (int off = 32; off; off >>= 1) ss += __shfl_xor(ss, off);
    float inv = rsqrtf(ss * (1.0f / 128.0f) + 1.1920928955078125e-07f);
    x0 *= inv; x1 *= inv;

    float freq = exp2f(-(float)lane * 0.20762050593046013f);
    float ang = (float)t * freq;
    float s, c;
    sincosf(ang, &s, &c);
    float o0 = x0 * c - x1 * s;
    float o1 = x1 * c + x0 * s;
    base[lane]      = (__bf16)(o0 * gain);
    base[lane + 64] = (__bf16)(o1 * gain);
}

// ---------------------------------------------------------------------------
// V transpose: vt[b][c][t] = kv[b][t][512 + c]   (c = kvh*128+d in [0,512))
// ---------------------------------------------------------------------------
__global__ __launch_bounds__(256) void transpose_v(
    const __bf16* __restrict__ kv, __bf16* __restrict__ vtout)
{
    __shared__ __bf16 tile[64][65];
    const int b = blockIdx.z;
    const int t0 = blockIdx.x * 64, c0 = blockIdx.y * 64;
    const __bf16* vb = kv + (size_t)b * 2048 * 1024 + 512;
    __bf16* vtb = vtout + (size_t)b * 512 * 2048;
    const int j = threadIdx.x & 63;
    const int r0 = threadIdx.x >> 6;
#pragma unroll
    for (int i = 0; i < 16; ++i) {
        int r = r0 + i * 4;
        tile[r][j] = vb[(size_t)(t0 + r) * 1024 + c0 + j];
    }
    __syncthreads();
#pragma unroll
    for (int i = 0; i < 16; ++i) {
        int r = r0 + i * 4;
        vtb[(size_t)(c0 + r) * 2048 + t0 + j] = tile[j][r];
    }
}

// ---------------------------------------------------------------------------
// Flash attention (causal, GQA).  Block = (qtile, b*H+h), 256 threads.
// Fixed-max softmax (RMSNorm bounds scores), XOR-swizzled LDS, Q in regs.
// ---------------------------------------------------------------------------
__global__ __launch_bounds__(256, 4) void attn(
    const __bf16* __restrict__ q, const __bf16* __restrict__ kv,
    const __bf16* __restrict__ vt, __bf16* __restrict__ y,
    const float* __restrict__ q_gain)
{
    const int qt = 31 - blockIdx.x;  // big blocks launch first
    const int bh = blockIdx.y;
    const int b = bh >> 4, h = bh & 15, kvh = h >> 2;
    const int tid = threadIdx.x;
    const int wave = tid >> 6, lane = tid & 63;
    const int quad = lane >> 4, l16 = lane & 15;

    __shared__ __bf16 Ks[64 * 128];    // [kv_row][d]  chunk c at c^(row&15)
    __shared__ __bf16 Vts[128 * 64];   // [d][kv_row]  chunk c at c^(row&7)
    __shared__ __bf16 Ps[4 * 16 * 64]; // per-wave [qrow][kv] chunk c^(row&7)

    const int qt0 = qt * 64;
    const int wq = wave * 16;   // this wave's 16 q-rows (local)

    // Q fragments straight from global (A-layout: 8 contiguous bf16 / lane)
    const size_t qrow = ((size_t)b * 2048 + qt0 + wq + l16) * 2048 + h * 128;
    bf16x8 qf[4];
#pragma unroll
    for (int t = 0; t < 4; ++t)
        qf[t] = *(const bf16x8*)(q + qrow + t * 32 + quad * 8);

    f32x4 oacc[8] = {};
    float lsum[4] = {0.f, 0.f, 0.f, 0.f};

    const float sm_scale = 0.12754635f;          // 1/sqrt(128) * log2(e)
    const float mfix = 11.5f * fabsf(q_gain[h]); // >= max possible score

    const size_t kbase = (size_t)b * 2048 * 1024 + kvh * 128;      // stride 1024
    const size_t vtbase = (size_t)(b * 4 + kvh) * 128 * 2048;      // stride 2048

    const int rowK = lane >> 4, pcK = lane & 15;
    const int rowV = lane >> 3, pcV = lane & 7;

    for (int jt = 0; jt <= qt; ++jt) {
        const int j0 = jt * 64;
        __syncthreads();
#pragma unroll
        for (int r = 0; r < 4; ++r) {
            int rrK = (r * 4 + wave) * 4 + rowK;
            int cK = pcK ^ (rrK & 15);
            load_lds16(kv + kbase + (size_t)(j0 + rrK) * 1024 + cK * 8,
                       Ks + (r * 4 + wave) * 512);
            int rrV = (r * 4 + wave) * 8 + rowV;
            int cV = pcV ^ (rrV & 7);
            load_lds16(vt + vtbase + (size_t)rrV * 2048 + j0 + cV * 8,
                       Vts + (r * 4 + wave) * 512);
        }
        __syncthreads();

        // S strip (16 q-rows x 64 kv-cols) for this wave
        f32x4 sacc[4] = {};
#pragma unroll
        for (int nt = 0; nt < 4; ++nt)
#pragma unroll
            for (int t = 0; t < 4; ++t) {
                bf16x8 kf = *(const bf16x8*)(
                    Ks + (nt * 16 + l16) * 128 + ((t * 4 + quad) ^ l16) * 8);
                sacc[nt] = __builtin_amdgcn_mfma_f32_16x16x32_bf16(
                    qf[t], kf, sacc[nt], 0, 0, 0);
            }

        if (jt == qt) {  // diagonal tile: causal mask
#pragma unroll
            for (int nt = 0; nt < 4; ++nt) {
                int kg = nt * 16 + l16;
#pragma unroll
                for (int r = 0; r < 4; ++r)
                    if (kg > wq + quad * 4 + r) sacc[nt][r] = -3.0e38f;
            }
        }

        // fixed-max exp; per-lane partial row sums (reduced once at end)
        float p[4][4];
#pragma unroll
        for (int nt = 0; nt < 4; ++nt)
#pragma unroll
            for (int r = 0; r < 4; ++r) {
                float pv = exp2f((sacc[nt][r] - mfix) * sm_scale);
                p[nt][r] = pv;
                lsum[r] += pv;
            }

        // P: C-layout -> LDS (swizzled) -> A-layout (per-wave, no barrier)
        __bf16* Pw = Ps + wave * 1024;
#pragma unroll
        for (int nt = 0; nt < 4; ++nt)
#pragma unroll
            for (int r = 0; r < 4; ++r) {
                int row = quad * 4 + r;
                int pc = (nt * 2 + (l16 >> 3)) ^ (row & 7);
                Pw[row * 64 + pc * 8 + (l16 & 7)] = (__bf16)p[nt][r];
            }

#pragma unroll
        for (int kt = 0; kt < 2; ++kt) {
            bf16x8 pf = *(const bf16x8*)(
                Pw + l16 * 64 + ((kt * 4 + quad) ^ (l16 & 7)) * 8);
#pragma unroll
            for (int vn = 0; vn < 8; ++vn) {
                bf16x8 vf = *(const bf16x8*)(
                    Vts + (vn * 16 + l16) * 64 + ((kt * 4 + quad) ^ (l16 & 7)) * 8);
                oacc[vn] = __builtin_amdgcn_mfma_f32_16x16x32_bf16(
                    pf, vf, oacc[vn], 0, 0, 0);
            }
        }
    }

    // final l reduction across the 16 lanes holding each row
#pragma unroll
    for (int r = 0; r < 4; ++r)
#pragma unroll
        for (int off = 8; off; off >>= 1) lsum[r] += __shfl_xor(lsum[r], off);

    // epilogue: y[b][t][h*128+d]
    const size_t ybase = ((size_t)b * 2048 + qt0 + wq) * 2048 + h * 128;
#pragma unroll
    for (int r = 0; r < 4; ++r) {
        float inv = 1.0f / lsum[r];
        __bf16* yp = y + ybase + (size_t)(quad * 4 + r) * 2048 + l16;
#pragma unroll
        for (int vn = 0; vn < 8; ++vn)
            yp[vn * 16] = (__bf16)(oacc[vn][r] * inv);
    }
}

// ---------------------------------------------------------------------------
extern "C" void kernel_launch(void* const* d_in, const int* in_sizes, int n_in,
                              void* d_out, int out_size, void* d_ws, size_t ws_size,
                              hipStream_t stream) {
    const float* x     = (const float*)d_in[0];
    const float* Wq    = (const float*)d_in[1];
    const float* Wk    = (const float*)d_in[2];
    const float* Wv    = (const float*)d_in[3];
    const float* Wproj = (const float*)d_in[4];
    const float* qgain = (const float*)d_in[5];
    float* outp = (float*)d_out;

    // workspace layout (bf16 elems)
    __bf16* xb  = (__bf16*)d_ws;          // 16777216
    __bf16* Wqb = xb  + 16777216;         // 4194304
    __bf16* Wkb = Wqb + 4194304;          // 1048576  (Wkb+Wvb = fused [1024][2048])
    __bf16* Wvb = Wkb + 1048576;          // 1048576
    __bf16* Wpb = Wvb + 1048576;          // 4194304
    __bf16* q   = Wpb + 4194304;          // 16777216
    __bf16* kvb = q   + 16777216;         // 8388608  [4*2048][1024]: k|v fused
    __bf16* vt  = kvb + 8388608;          // 4194304  [4][512][2048]
    __bf16* y   = q;                      // alias: 1:1 tile correspondence, safe

    dim3 blk(256);
    cvt_f32_bf16<<<dim3(16777216 / 1024), blk, 0, stream>>>(x, xb, 16777216);
    cvt_f32_bf16<<<dim3(4194304 / 1024), blk, 0, stream>>>(Wq, Wqb, 4194304);
    cvt_f32_bf16<<<dim3(1048576 / 1024), blk, 0, stream>>>(Wk, Wkb, 1048576);
    cvt_f32_bf16<<<dim3(1048576 / 1024), blk, 0, stream>>>(Wv, Wvb, 1048576);
    cvt_f32_bf16<<<dim3(4194304 / 1024), blk, 0, stream>>>(Wproj, Wpb, 4194304);

    gemm_bt<__bf16><<<dim3(16, 64), blk, 0, stream>>>(xb, Wqb, q, 8192, 2048, 2048);
    gemm_bt<__bf16><<<dim3(8, 64), blk, 0, stream>>>(xb, Wkb, kvb, 8192, 1024, 2048);
    qk_norm_rope<<<dim3((4 * 2048 * (16 + 4)) / 4), blk, 0, stream>>>(q, kvb, qgain);
    transpose_v<<<dim3(32, 8, 4), blk, 0, stream>>>(kvb, vt);
    attn<<<dim3(32, 64), blk, 0, stream>>>(q, kvb, vt, y, qgain);
    gemm_bt<float><<<dim3(16, 64), blk, 0, stream>>>(y, Wpb, outp, 8192, 2048, 2048);
}